// Round 7
// baseline (3047.949 us; speedup 1.0000x reference)
//
#include <hip/hip_runtime.h>
#include <hip/hip_bf16.h>
#include <math.h>

// ---------------------------------------------------------------------------
// LSTM text classifier forward, MI355X/gfx950.  Round 7.
//
// R6 post-mortem: per-step cross-CU sync is structurally ~2us (L3 propagate
// + poll RT + store-ack drains); handshake tuning moved it 0.5us over two
// rounds. Per-CU VALUBusy 54% = waves spinning. The sync must go entirely.
//
// R7: ONE CU per batch group, zero inter-block communication.
//   4 blocks x 512 thr (8 waves). Block g owns batches 16g..16g+16 and the
//   FULL 256-unit hidden update. U (512 KB bf16) made CU-resident:
//     - AGPR 256 KB: wave w holds unit-tile A=2w, all 4 gates, ks0..7
//       (32 frags = 128 AGPRs; exact R5/R6 "+a" pin + asm MFMA pattern).
//     - LDS 128 KB: unit-tile B=2w+1, ks0..3 (ds_read_b128 -> MFMA).
//     - L2 stream 128 KB/step: tile B ks4..7, loaded per step in 4-frag
//       groups (<=32 VGPR live) via asm-opaqued pointer (defeats LICM),
//       consumed last so L2 latency hides under LDS-sourced MFMAs.
//   h double-buffered in LDS; one __syncthreads per step; c in registers.
//   Per-step: MFMA 512x4.85=2483cyc | LDS ~2300 | L2 ~2000, overlapped.
//
// MFMA 16x16x32 bf16 layouts (m89/m91):
//   A[m][k]: m=lane&15, k=(lane>>4)*8+j      B[k][n]: n=lane&15, same k
//   C/D:     col=lane&15, row=(lane>>4)*4+reg
// ---------------------------------------------------------------------------

typedef __bf16 bf16_t;
typedef bf16_t bf16x8 __attribute__((ext_vector_type(8)));
typedef bf16_t bf16x4 __attribute__((ext_vector_type(4)));
typedef float  f32x4  __attribute__((ext_vector_type(4)));
typedef unsigned long long u64;

#define T_SZ 512
#define HID 256
#define G4 1024
#define NCLS 20

// workspace layout (bytes)
#define WS_UPACK 0u
#define WS_WPACK (512u * 1024u)
#define WS_HFIN  (1024u * 1024u)                  // 64 KB
#define WS_XZ    (2u * 1024u * 1024u)             // 64 MB
// total: 66 MB

// ---------------------------------------------------------------------------
// Pack W and U (f32 [256][1024]) into bf16 B-fragment order:
// frag f = (ntile*8 + kstep)*64 + lane ; element j=0..7
// value = M[kstep*32 + (lane>>4)*8 + j][ntile*16 + (lane&15)]
// ---------------------------------------------------------------------------
__global__ void pack_weights(const float* __restrict__ W, const float* __restrict__ U,
                             bf16_t* __restrict__ Wp, bf16_t* __restrict__ Up) {
    int tid  = blockIdx.x * blockDim.x + threadIdx.x;   // 0..262143
    int j    = tid & 7;
    int lane = (tid >> 3) & 63;
    int ks   = (tid >> 9) & 7;
    int nt   = tid >> 12;
    int row  = ks * 32 + ((lane >> 4) << 3) + j;
    int col  = nt * 16 + (lane & 15);
    Wp[tid] = (bf16_t)W[row * G4 + col];
    Up[tid] = (bf16_t)U[row * G4 + col];
}

// ---------------------------------------------------------------------------
// Phase A: xz = emb[x] @ W + bias, stored bf16 in C-fragment order:
//   xz2[((t*4 + bchunk)*64 + ntile)*64 + lane] = bf16x4 {r=0..3}
// value[r] = z[batch = bchunk*16 + (lane>>4)*4 + r][col = ntile*16 + (lane&15)]
// ---------------------------------------------------------------------------
__global__ __launch_bounds__(256) void xz_gemm(const int* __restrict__ x,
                                               const float* __restrict__ emb,
                                               const bf16_t* __restrict__ Wp,
                                               const float* __restrict__ bias,
                                               bf16x4* __restrict__ xz2) {
    int nb   = blockIdx.x & 7;
    int t    = blockIdx.x >> 3;
    int w    = threadIdx.x >> 6;
    int lane = threadIdx.x & 63;
    int l15  = lane & 15;
    int quad = lane >> 4;

    int b_row = w * 16 + l15;
    int tok   = x[b_row * T_SZ + t];
    const float* erow = emb + (size_t)tok * 256;

    bf16x8 afrag[8];
#pragma unroll
    for (int ks = 0; ks < 8; ks++) {
        const float4* p = (const float4*)(erow + ks * 32 + quad * 8);
        float4 v0 = p[0], v1 = p[1];
        bf16x8 a;
        a[0] = (bf16_t)v0.x; a[1] = (bf16_t)v0.y; a[2] = (bf16_t)v0.z; a[3] = (bf16_t)v0.w;
        a[4] = (bf16_t)v1.x; a[5] = (bf16_t)v1.y; a[6] = (bf16_t)v1.z; a[7] = (bf16_t)v1.w;
        afrag[ks] = a;
    }

    const bf16x8* Wf = (const bf16x8*)Wp;

#pragma unroll
    for (int nt = 0; nt < 8; nt++) {
        int ntg = nb * 8 + nt;
        float bv = bias[ntg * 16 + l15];
        f32x4 acc = {bv, bv, bv, bv};
        const bf16x8* bp = Wf + (size_t)(ntg * 8) * 64 + lane;
#pragma unroll
        for (int ks = 0; ks < 8; ks++) {
            bf16x8 bfrag = bp[ks * 64];
            acc = __builtin_amdgcn_mfma_f32_16x16x32_bf16(afrag[ks], bfrag, acc, 0, 0, 0);
        }
        bf16x4 hv;
#pragma unroll
        for (int r = 0; r < 4; r++) hv[r] = (bf16_t)acc[r];
        xz2[((size_t)(t * 4 + w) * 64 + ntg) * 64 + lane] = hv;
    }
}

__device__ __forceinline__ float sigmoid_f(float z) {
    return 1.0f / (1.0f + __expf(-z));
}
__device__ __forceinline__ float tanh_f(float z) {
    float e = __expf(2.0f * z);
    return 1.0f - 2.0f / (e + 1.0f);
}

// MFMA with B operand in AGPR class (gfx950 unified file; proven R5/R6).
__device__ __forceinline__ void mfma_aB(f32x4& d, bf16x8 a, bf16x8 b) {
    asm("v_mfma_f32_16x16x32_bf16 %0, %1, %2, %0" : "+v"(d) : "v"(a), "a"(b));
}

// ---------------------------------------------------------------------------
// Phase B: recurrence. Grid: 4 blocks x 512 thr (8 waves). NO inter-block
// communication. Wave w owns unit-tiles A=2w (AGPR U) and B=2w+1
// (U: ks0..3 LDS-resident, ks4..7 streamed from L2 each step).
// ---------------------------------------------------------------------------
__global__ __launch_bounds__(512, 2) void lstm_solo(const bf16x4* __restrict__ xz2,
                                                    const bf16_t* __restrict__ Up,
                                                    float* __restrict__ hfin) {
    __shared__ bf16x8 ulds[128 * 64];                  // 128 KB: tile-B ks0..3
    __shared__ __align__(16) bf16_t h_lds[2][16][264]; // 16.9 KB dbl-buffered

    const int g    = blockIdx.x;
    const int w    = threadIdx.x >> 6;
    const int lane = threadIdx.x & 63;
    const int l15  = lane & 15;
    const int quad = lane >> 4;
    const int ntA  = 2 * w;        // this wave's unit-tile A (units 32w..32w+16)
    const int ntB  = 2 * w + 1;    // unit-tile B (units 32w+16..32w+32)

    const bf16x8* Uf  = (const bf16x8*)Up + lane;
    const bf16x8* Ufr = (const bf16x8*)Up;

    // ---- tile A U -> AGPRs (once; R5/R6-proven pin) ------------------------
    bf16x8 uA[4][8];
#pragma unroll
    for (int G = 0; G < 4; G++)
#pragma unroll
        for (int ks = 0; ks < 8; ks++)
            uA[G][ks] = Uf[((G * 16 + ntA) * 8 + ks) * 64];
    asm volatile("" : "+a"(uA[0][0]), "+a"(uA[0][1]), "+a"(uA[0][2]), "+a"(uA[0][3]),
                      "+a"(uA[0][4]), "+a"(uA[0][5]), "+a"(uA[0][6]), "+a"(uA[0][7]));
    asm volatile("" : "+a"(uA[1][0]), "+a"(uA[1][1]), "+a"(uA[1][2]), "+a"(uA[1][3]),
                      "+a"(uA[1][4]), "+a"(uA[1][5]), "+a"(uA[1][6]), "+a"(uA[1][7]));
    asm volatile("" : "+a"(uA[2][0]), "+a"(uA[2][1]), "+a"(uA[2][2]), "+a"(uA[2][3]),
                      "+a"(uA[2][4]), "+a"(uA[2][5]), "+a"(uA[2][6]), "+a"(uA[2][7]));
    asm volatile("" : "+a"(uA[3][0]), "+a"(uA[3][1]), "+a"(uA[3][2]), "+a"(uA[3][3]),
                      "+a"(uA[3][4]), "+a"(uA[3][5]), "+a"(uA[3][6]), "+a"(uA[3][7]));

    // ---- tile B ks0..3 -> LDS (once); frag index fi = w*16 + G*4 + ks ------
    for (int i = threadIdx.x; i < 128 * 64; i += 512) {
        int fi = i >> 6, ln = i & 63;
        int w2 = fi >> 4, G = (fi >> 2) & 3, ks = fi & 3;
        ulds[i] = Ufr[((G * 16 + 2 * w2 + 1) * 8 + ks) * 64 + ln];
    }
    for (int i = threadIdx.x; i < 2 * 16 * 264; i += 512)
        (&h_lds[0][0][0])[i] = (bf16_t)0.0f;           // h0 = 0

    f32x4 cstA = {0.f, 0.f, 0.f, 0.f};
    f32x4 cstB = {0.f, 0.f, 0.f, 0.f};

    bf16x4 xzvA[4], xzvB[4];   // prefetched xz fragments
#pragma unroll
    for (int G = 0; G < 4; G++) {
        xzvA[G] = xz2[((size_t)(0 * 4 + g) * 64 + (G * 16 + ntA)) * 64 + lane];
        xzvB[G] = xz2[((size_t)(0 * 4 + g) * 64 + (G * 16 + ntB)) * 64 + lane];
    }

    __syncthreads();

    for (int t = 0; t < T_SZ; t++) {
        const int buf  = t & 1;
        const int nbuf = buf ^ 1;

        // A-frags: h_t for batches l15, k-slice quad*8 (shared by both tiles)
        bf16x8 af[8];
#pragma unroll
        for (int ks = 0; ks < 8; ks++)
            af[ks] = *(const bf16x8*)&h_lds[buf][l15][ks * 32 + quad * 8];

        // capture current xz into accumulators BEFORE prefetch overwrites
        f32x4 aA[4], aB[4];
#pragma unroll
        for (int G = 0; G < 4; G++) {
            aA[G] = f32x4{(float)xzvA[G][0], (float)xzvA[G][1], (float)xzvA[G][2], (float)xzvA[G][3]};
            aB[G] = f32x4{(float)xzvB[G][0], (float)xzvB[G][1], (float)xzvB[G][2], (float)xzvB[G][3]};
        }

        // ---- tile A MFMAs: all-AGPR B operands ----------------------------
#pragma unroll
        for (int ks = 0; ks < 8; ks++)
#pragma unroll
            for (int G = 0; G < 4; G++)
                mfma_aB(aA[G], af[ks], uA[G][ks]);

        // prefetch next step's xz (HBM; lands during tile B + barrier)
        if (t + 1 < T_SZ) {
#pragma unroll
            for (int G = 0; G < 4; G++) {
                xzvA[G] = xz2[((size_t)((t + 1) * 4 + g) * 64 + (G * 16 + ntA)) * 64 + lane];
                xzvB[G] = xz2[((size_t)((t + 1) * 4 + g) * 64 + (G * 16 + ntB)) * 64 + lane];
            }
        }

        // ---- tile A gates + state -----------------------------------------
        {
            float hv[4];
#pragma unroll
            for (int r = 0; r < 4; r++) {
                float ig = sigmoid_f(aA[0][r]);
                float fg = sigmoid_f(aA[1][r]);
                float gg = tanh_f(aA[2][r]);
                float og = sigmoid_f(aA[3][r]);
                float cn = fg * cstA[r] + ig * gg;
                cstA[r] = cn;
                hv[r] = og * tanh_f(cn);
            }
            if (t == T_SZ - 1) {
#pragma unroll
                for (int r = 0; r < 4; r++)
                    hfin[(g * 16 + quad * 4 + r) * HID + 32 * w + l15] = hv[r];
            } else {
#pragma unroll
                for (int r = 0; r < 4; r++)
                    h_lds[nbuf][quad * 4 + r][32 * w + l15] = (bf16_t)hv[r];
            }
        }

        // ---- tile B: ks0..3 from LDS, ks4..7 streamed from L2 -------------
        // opaque pointer per iteration: blocks LICM from hoisting the stream
        uintptr_t pU = (uintptr_t)Up;
        asm volatile("" : "+v"(pU));
        const bf16x8* Ufs = (const bf16x8*)pU + lane;

        bf16x8 s0[4], s1[4];
#pragma unroll
        for (int j = 0; j < 4; j++) s0[j] = Ufs[((0 * 16 + ntB) * 8 + 4 + j) * 64];
#pragma unroll
        for (int j = 0; j < 4; j++) s1[j] = Ufs[((1 * 16 + ntB) * 8 + 4 + j) * 64];

        unsigned uo = 0;                 // opaque LDS offset (blocks ds_read LICM)
        asm volatile("" : "+v"(uo));
        const bf16x8* ub = ulds + ((unsigned)(w * 16) << 6) + lane + uo;
#pragma unroll
        for (int ks = 0; ks < 4; ks++)
#pragma unroll
            for (int G = 0; G < 4; G++) {
                bf16x8 bfrag = ub[(unsigned)((G * 4 + ks) << 6)];
                aB[G] = __builtin_amdgcn_mfma_f32_16x16x32_bf16(af[ks], bfrag, aB[G], 0, 0, 0);
            }

        bf16x8 s2[4];
#pragma unroll
        for (int j = 0; j < 4; j++) s2[j] = Ufs[((2 * 16 + ntB) * 8 + 4 + j) * 64];
#pragma unroll
        for (int j = 0; j < 4; j++)
            aB[0] = __builtin_amdgcn_mfma_f32_16x16x32_bf16(af[4 + j], s0[j], aB[0], 0, 0, 0);

        bf16x8 s3[4];
#pragma unroll
        for (int j = 0; j < 4; j++) s3[j] = Ufs[((3 * 16 + ntB) * 8 + 4 + j) * 64];
#pragma unroll
        for (int j = 0; j < 4; j++)
            aB[1] = __builtin_amdgcn_mfma_f32_16x16x32_bf16(af[4 + j], s1[j], aB[1], 0, 0, 0);
#pragma unroll
        for (int j = 0; j < 4; j++)
            aB[2] = __builtin_amdgcn_mfma_f32_16x16x32_bf16(af[4 + j], s2[j], aB[2], 0, 0, 0);
#pragma unroll
        for (int j = 0; j < 4; j++)
            aB[3] = __builtin_amdgcn_mfma_f32_16x16x32_bf16(af[4 + j], s3[j], aB[3], 0, 0, 0);

        // ---- tile B gates + state -----------------------------------------
        {
            float hv[4];
#pragma unroll
            for (int r = 0; r < 4; r++) {
                float ig = sigmoid_f(aB[0][r]);
                float fg = sigmoid_f(aB[1][r]);
                float gg = tanh_f(aB[2][r]);
                float og = sigmoid_f(aB[3][r]);
                float cn = fg * cstB[r] + ig * gg;
                cstB[r] = cn;
                hv[r] = og * tanh_f(cn);
            }
            if (t == T_SZ - 1) {
#pragma unroll
                for (int r = 0; r < 4; r++)
                    hfin[(g * 16 + quad * 4 + r) * HID + 32 * w + 16 + l15] = hv[r];
            } else {
#pragma unroll
                for (int r = 0; r < 4; r++)
                    h_lds[nbuf][quad * 4 + r][32 * w + 16 + l15] = (bf16_t)hv[r];
            }
        }

        if (t == T_SZ - 1) break;   // uniform exit
        __syncthreads();            // h_{t+1} complete in LDS
    }
}

// ---------------------------------------------------------------------------
// Phase C: logits = h_T @ Wd + bd; softmax. One block per batch row.
// ---------------------------------------------------------------------------
__global__ void head(const float* __restrict__ hfin, const float* __restrict__ Wd,
                     const float* __restrict__ bd, float* __restrict__ out) {
    __shared__ float hrow[HID];
    __shared__ float lg[32];
    __shared__ float ex[32];
    int b = blockIdx.x, tid = threadIdx.x;   // 64 threads
    for (int i = tid; i < HID; i += 64) hrow[i] = hfin[b * HID + i];
    __syncthreads();
    if (tid < NCLS) {
        float acc = bd[tid];
        for (int k = 0; k < HID; k++) acc = fmaf(hrow[k], Wd[k * NCLS + tid], acc);
        lg[tid] = acc;
    }
    __syncthreads();
    if (tid < NCLS) {
        float m = -1e30f;
        for (int jj = 0; jj < NCLS; jj++) m = fmaxf(m, lg[jj]);
        ex[tid] = __expf(lg[tid] - m);
    }
    __syncthreads();
    if (tid < NCLS) {
        float sden = 0.0f;
        for (int jj = 0; jj < NCLS; jj++) sden += ex[jj];
        out[b * NCLS + tid] = ex[tid] / sden;
    }
}

// ---------------------------------------------------------------------------
extern "C" void kernel_launch(void* const* d_in, const int* in_sizes, int n_in,
                              void* d_out, int out_size, void* d_ws, size_t ws_size,
                              hipStream_t stream) {
    const int*   x    = (const int*)d_in[0];
    const float* emb  = (const float*)d_in[1];
    const float* W    = (const float*)d_in[2];
    const float* U    = (const float*)d_in[3];
    const float* bias = (const float*)d_in[4];
    const float* Wd   = (const float*)d_in[5];
    const float* bd   = (const float*)d_in[6];
    float* out = (float*)d_out;

    char* ws = (char*)d_ws;
    bf16_t* Up  = (bf16_t*)(ws + WS_UPACK);
    bf16_t* Wp  = (bf16_t*)(ws + WS_WPACK);
    float*  hf  = (float*)(ws + WS_HFIN);
    bf16x4* xz2 = (bf16x4*)(ws + WS_XZ);

    pack_weights<<<dim3(1024), dim3(256), 0, stream>>>(W, U, Wp, Up);
    xz_gemm<<<dim3(4096), dim3(256), 0, stream>>>(x, emb, Wp, bias, xz2);
    lstm_solo<<<dim3(4), dim3(512), 0, stream>>>(xz2, Up, hf);
    head<<<dim3(64), dim3(64), 0, stream>>>(hf, Wd, bd, out);
}

// Round 9
// 2400.797 us; speedup vs baseline: 1.2696x; 1.2696x over previous
//
#include <hip/hip_runtime.h>
#include <hip/hip_bf16.h>
#include <math.h>

// ---------------------------------------------------------------------------
// LSTM text classifier forward, MI355X/gfx950.  Round 9.
//
// R8 post-mortem: false-dep asm hacks under max register pressure broke
// correctness (timing-dependent, absmax 3.9e-3). Reverted to R7 (passed).
// R7's real problem: scheduler hoisted all 4 L2-stream groups to the BB top
// -> 64 VGPRs live -> scratch spill (VGPR pegged 128) -> 5.6us/step.
//
// R9 = R7 + __builtin_amdgcn_sched_barrier(0) fences (semantically inert,
// scheduling-only):
//   top:  load s0 (hides under af-reads + 32 tile-A MFMAs)   | F1
//   tile A MFMA -> gates A -> LDS-B ks0..3 MFMA              | F2
//   {load s1; consume s0} F3 {load s2; consume s1} F4
//   {load s3; consume s2} F5 {consume s3} -> gates B
// Max 2 stream groups (32 VGPRs) live; worst-point ~114 < 128 -> no spill.
// Checkpoint: VGPR_Count < 128.
//
// Structure recap (R7, PASSED): 4 blocks x 512 thr (8 waves), zero
// inter-block comm. Block g owns batches 16g..16g+16, full 256-unit update.
// U (512KB): AGPR 256KB (tile A=2w, "+a" pin + asm MFMA) | LDS 128KB
// (tile B=2w+1 ks0..3) | L2 stream 128KB/step (tile B ks4..7).
// h double-buffered in LDS; one __syncthreads/step; c in registers.
//
// MFMA 16x16x32 bf16 layouts (m89/m91):
//   A[m][k]: m=lane&15, k=(lane>>4)*8+j      B[k][n]: n=lane&15, same k
//   C/D:     col=lane&15, row=(lane>>4)*4+reg
// ---------------------------------------------------------------------------

typedef __bf16 bf16_t;
typedef bf16_t bf16x8 __attribute__((ext_vector_type(8)));
typedef bf16_t bf16x4 __attribute__((ext_vector_type(4)));
typedef float  f32x4  __attribute__((ext_vector_type(4)));
typedef unsigned long long u64;

#define T_SZ 512
#define HID 256
#define G4 1024
#define NCLS 20

// workspace layout (bytes)
#define WS_UPACK 0u
#define WS_WPACK (512u * 1024u)
#define WS_HFIN  (1024u * 1024u)                  // 64 KB
#define WS_XZ    (2u * 1024u * 1024u)             // 64 MB
// total: 66 MB

// ---------------------------------------------------------------------------
// Pack W and U (f32 [256][1024]) into bf16 B-fragment order:
// frag f = (ntile*8 + kstep)*64 + lane ; element j=0..7
// value = M[kstep*32 + (lane>>4)*8 + j][ntile*16 + (lane&15)]
// ---------------------------------------------------------------------------
__global__ void pack_weights(const float* __restrict__ W, const float* __restrict__ U,
                             bf16_t* __restrict__ Wp, bf16_t* __restrict__ Up) {
    int tid  = blockIdx.x * blockDim.x + threadIdx.x;   // 0..262143
    int j    = tid & 7;
    int lane = (tid >> 3) & 63;
    int ks   = (tid >> 9) & 7;
    int nt   = tid >> 12;
    int row  = ks * 32 + ((lane >> 4) << 3) + j;
    int col  = nt * 16 + (lane & 15);
    Wp[tid] = (bf16_t)W[row * G4 + col];
    Up[tid] = (bf16_t)U[row * G4 + col];
}

// ---------------------------------------------------------------------------
// Phase A: xz = emb[x] @ W + bias, stored bf16 in C-fragment order:
//   xz2[((t*4 + bchunk)*64 + ntile)*64 + lane] = bf16x4 {r=0..3}
// value[r] = z[batch = bchunk*16 + (lane>>4)*4 + r][col = ntile*16 + (lane&15)]
// ---------------------------------------------------------------------------
__global__ __launch_bounds__(256) void xz_gemm(const int* __restrict__ x,
                                               const float* __restrict__ emb,
                                               const bf16_t* __restrict__ Wp,
                                               const float* __restrict__ bias,
                                               bf16x4* __restrict__ xz2) {
    int nb   = blockIdx.x & 7;
    int t    = blockIdx.x >> 3;
    int w    = threadIdx.x >> 6;
    int lane = threadIdx.x & 63;
    int l15  = lane & 15;
    int quad = lane >> 4;

    int b_row = w * 16 + l15;
    int tok   = x[b_row * T_SZ + t];
    const float* erow = emb + (size_t)tok * 256;

    bf16x8 afrag[8];
#pragma unroll
    for (int ks = 0; ks < 8; ks++) {
        const float4* p = (const float4*)(erow + ks * 32 + quad * 8);
        float4 v0 = p[0], v1 = p[1];
        bf16x8 a;
        a[0] = (bf16_t)v0.x; a[1] = (bf16_t)v0.y; a[2] = (bf16_t)v0.z; a[3] = (bf16_t)v0.w;
        a[4] = (bf16_t)v1.x; a[5] = (bf16_t)v1.y; a[6] = (bf16_t)v1.z; a[7] = (bf16_t)v1.w;
        afrag[ks] = a;
    }

    const bf16x8* Wf = (const bf16x8*)Wp;

#pragma unroll
    for (int nt = 0; nt < 8; nt++) {
        int ntg = nb * 8 + nt;
        float bv = bias[ntg * 16 + l15];
        f32x4 acc = {bv, bv, bv, bv};
        const bf16x8* bp = Wf + (size_t)(ntg * 8) * 64 + lane;
#pragma unroll
        for (int ks = 0; ks < 8; ks++) {
            bf16x8 bfrag = bp[ks * 64];
            acc = __builtin_amdgcn_mfma_f32_16x16x32_bf16(afrag[ks], bfrag, acc, 0, 0, 0);
        }
        bf16x4 hv;
#pragma unroll
        for (int r = 0; r < 4; r++) hv[r] = (bf16_t)acc[r];
        xz2[((size_t)(t * 4 + w) * 64 + ntg) * 64 + lane] = hv;
    }
}

__device__ __forceinline__ float sigmoid_f(float z) {
    return 1.0f / (1.0f + __expf(-z));
}
__device__ __forceinline__ float tanh_f(float z) {
    float e = __expf(2.0f * z);
    return 1.0f - 2.0f / (e + 1.0f);
}

// MFMA with B operand in AGPR class (gfx950 unified file; proven R5-R7).
__device__ __forceinline__ void mfma_aB(f32x4& d, bf16x8 a, bf16x8 b) {
    asm("v_mfma_f32_16x16x32_bf16 %0, %1, %2, %0" : "+v"(d) : "v"(a), "a"(b));
}

// ---------------------------------------------------------------------------
// Phase B: recurrence. Grid: 4 blocks x 512 thr (8 waves). NO inter-block
// communication. Wave w: tile A=2w (AGPR U), tile B=2w+1 (ks0..3 LDS,
// ks4..7 L2-streamed, depth-2 pipeline enforced by sched_barrier fences).
// ---------------------------------------------------------------------------
__global__ __launch_bounds__(512, 2) void lstm_solo(const bf16x4* __restrict__ xz2,
                                                    const bf16_t* __restrict__ Up,
                                                    float* __restrict__ hfin) {
    __shared__ bf16x8 ulds[128 * 64];                  // 128 KB: tile-B ks0..3
    __shared__ __align__(16) bf16_t h_lds[2][16][264]; // 16.9 KB dbl-buffered

    const int g    = blockIdx.x;
    const int w    = threadIdx.x >> 6;
    const int lane = threadIdx.x & 63;
    const int l15  = lane & 15;
    const int quad = lane >> 4;
    const int ntA  = 2 * w;        // units 32w..32w+16
    const int ntB  = 2 * w + 1;    // units 32w+16..32w+32

    const bf16x8* Uf  = (const bf16x8*)Up + lane;
    const bf16x8* Ufr = (const bf16x8*)Up;

    // ---- tile A U -> AGPRs (once; proven pin) ------------------------------
    bf16x8 uA[4][8];
#pragma unroll
    for (int G = 0; G < 4; G++)
#pragma unroll
        for (int ks = 0; ks < 8; ks++)
            uA[G][ks] = Uf[((G * 16 + ntA) * 8 + ks) * 64];
    asm volatile("" : "+a"(uA[0][0]), "+a"(uA[0][1]), "+a"(uA[0][2]), "+a"(uA[0][3]),
                      "+a"(uA[0][4]), "+a"(uA[0][5]), "+a"(uA[0][6]), "+a"(uA[0][7]));
    asm volatile("" : "+a"(uA[1][0]), "+a"(uA[1][1]), "+a"(uA[1][2]), "+a"(uA[1][3]),
                      "+a"(uA[1][4]), "+a"(uA[1][5]), "+a"(uA[1][6]), "+a"(uA[1][7]));
    asm volatile("" : "+a"(uA[2][0]), "+a"(uA[2][1]), "+a"(uA[2][2]), "+a"(uA[2][3]),
                      "+a"(uA[2][4]), "+a"(uA[2][5]), "+a"(uA[2][6]), "+a"(uA[2][7]));
    asm volatile("" : "+a"(uA[3][0]), "+a"(uA[3][1]), "+a"(uA[3][2]), "+a"(uA[3][3]),
                      "+a"(uA[3][4]), "+a"(uA[3][5]), "+a"(uA[3][6]), "+a"(uA[3][7]));

    // ---- tile B ks0..3 -> LDS (once); frag fi = w*16 + G*4 + ks ------------
    for (int i = threadIdx.x; i < 128 * 64; i += 512) {
        int fi = i >> 6, ln = i & 63;
        int w2 = fi >> 4, G = (fi >> 2) & 3, ks = fi & 3;
        ulds[i] = Ufr[((G * 16 + 2 * w2 + 1) * 8 + ks) * 64 + ln];
    }
    for (int i = threadIdx.x; i < 2 * 16 * 264; i += 512)
        (&h_lds[0][0][0])[i] = (bf16_t)0.0f;           // h0 = 0

    f32x4 cstA = {0.f, 0.f, 0.f, 0.f};
    f32x4 cstB = {0.f, 0.f, 0.f, 0.f};

    bf16x4 xzvA[4], xzvB[4];
#pragma unroll
    for (int G = 0; G < 4; G++) {
        xzvA[G] = xz2[((size_t)(0 * 4 + g) * 64 + (G * 16 + ntA)) * 64 + lane];
        xzvB[G] = xz2[((size_t)(0 * 4 + g) * 64 + (G * 16 + ntB)) * 64 + lane];
    }

    __syncthreads();

    for (int t = 0; t < T_SZ; t++) {
        const int buf  = t & 1;
        const int nbuf = buf ^ 1;

        // opaque stream base (blocks LICM of the loop-invariant U stream)
        uintptr_t pU = (uintptr_t)Up;
        asm volatile("" : "+v"(pU));
        const bf16x8* Ufs = (const bf16x8*)pU + lane;

        // ---- issue stream group 0 (G=0 ks4..7); hides under tile A ---------
        bf16x8 s0[4];
#pragma unroll
        for (int j = 0; j < 4; j++) s0[j] = Ufs[((0 * 16 + ntB) * 8 + 4 + j) * 64];
        __builtin_amdgcn_sched_barrier(0);   // F1: s0 issued first, stays put

        // A-frags: h_t (shared by both tiles)
        bf16x8 af[8];
#pragma unroll
        for (int ks = 0; ks < 8; ks++)
            af[ks] = *(const bf16x8*)&h_lds[buf][l15][ks * 32 + quad * 8];

        // capture current xz into accumulators (R7 position)
        f32x4 aA[4], aB[4];
#pragma unroll
        for (int G = 0; G < 4; G++) {
            aA[G] = f32x4{(float)xzvA[G][0], (float)xzvA[G][1], (float)xzvA[G][2], (float)xzvA[G][3]};
            aB[G] = f32x4{(float)xzvB[G][0], (float)xzvB[G][1], (float)xzvB[G][2], (float)xzvB[G][3]};
        }

        // ---- tile A MFMAs: all-AGPR B operands -----------------------------
#pragma unroll
        for (int ks = 0; ks < 8; ks++)
#pragma unroll
            for (int G = 0; G < 4; G++)
                mfma_aB(aA[G], af[ks], uA[G][ks]);

        // prefetch next step's xz (R7 position)
        if (t + 1 < T_SZ) {
#pragma unroll
            for (int G = 0; G < 4; G++) {
                xzvA[G] = xz2[((size_t)((t + 1) * 4 + g) * 64 + (G * 16 + ntA)) * 64 + lane];
                xzvB[G] = xz2[((size_t)((t + 1) * 4 + g) * 64 + (G * 16 + ntB)) * 64 + lane];
            }
        }

        // ---- tile A gates + state ------------------------------------------
        {
            float hv[4];
#pragma unroll
            for (int r = 0; r < 4; r++) {
                float ig = sigmoid_f(aA[0][r]);
                float fg = sigmoid_f(aA[1][r]);
                float gg = tanh_f(aA[2][r]);
                float og = sigmoid_f(aA[3][r]);
                float cn = fg * cstA[r] + ig * gg;
                cstA[r] = cn;
                hv[r] = og * tanh_f(cn);
            }
            if (t == T_SZ - 1) {
#pragma unroll
                for (int r = 0; r < 4; r++)
                    hfin[(g * 16 + quad * 4 + r) * HID + 32 * w + l15] = hv[r];
            } else {
#pragma unroll
                for (int r = 0; r < 4; r++)
                    h_lds[nbuf][quad * 4 + r][32 * w + l15] = (bf16_t)hv[r];
            }
        }

        // ---- tile B ks0..3 from LDS ----------------------------------------
        unsigned uo = 0;                 // opaque offset: blocks ds_read hoist
        asm volatile("" : "+v"(uo));
        const bf16x8* ub = ulds + ((unsigned)(w * 16) << 6) + lane + uo;
#pragma unroll
        for (int ks = 0; ks < 4; ks++)
#pragma unroll
            for (int G = 0; G < 4; G++) {
                bf16x8 bfrag = ub[(unsigned)((G * 4 + ks) << 6)];
                aB[G] = __builtin_amdgcn_mfma_f32_16x16x32_bf16(af[ks], bfrag, aB[G], 0, 0, 0);
            }

        // ---- fenced depth-2 stream pipeline (max 2 groups = 32 VGPR live) --
        __builtin_amdgcn_sched_barrier(0);   // F2
        bf16x8 s1[4];
#pragma unroll
        for (int j = 0; j < 4; j++) s1[j] = Ufs[((1 * 16 + ntB) * 8 + 4 + j) * 64];
#pragma unroll
        for (int j = 0; j < 4; j++)
            aB[0] = __builtin_amdgcn_mfma_f32_16x16x32_bf16(af[4 + j], s0[j], aB[0], 0, 0, 0);

        __builtin_amdgcn_sched_barrier(0);   // F3
        bf16x8 s2[4];
#pragma unroll
        for (int j = 0; j < 4; j++) s2[j] = Ufs[((2 * 16 + ntB) * 8 + 4 + j) * 64];
#pragma unroll
        for (int j = 0; j < 4; j++)
            aB[1] = __builtin_amdgcn_mfma_f32_16x16x32_bf16(af[4 + j], s1[j], aB[1], 0, 0, 0);

        __builtin_amdgcn_sched_barrier(0);   // F4
        bf16x8 s3[4];
#pragma unroll
        for (int j = 0; j < 4; j++) s3[j] = Ufs[((3 * 16 + ntB) * 8 + 4 + j) * 64];
#pragma unroll
        for (int j = 0; j < 4; j++)
            aB[2] = __builtin_amdgcn_mfma_f32_16x16x32_bf16(af[4 + j], s2[j], aB[2], 0, 0, 0);

        __builtin_amdgcn_sched_barrier(0);   // F5
#pragma unroll
        for (int j = 0; j < 4; j++)
            aB[3] = __builtin_amdgcn_mfma_f32_16x16x32_bf16(af[4 + j], s3[j], aB[3], 0, 0, 0);

        // ---- tile B gates + state ------------------------------------------
        {
            float hv[4];
#pragma unroll
            for (int r = 0; r < 4; r++) {
                float ig = sigmoid_f(aB[0][r]);
                float fg = sigmoid_f(aB[1][r]);
                float gg = tanh_f(aB[2][r]);
                float og = sigmoid_f(aB[3][r]);
                float cn = fg * cstB[r] + ig * gg;
                cstB[r] = cn;
                hv[r] = og * tanh_f(cn);
            }
            if (t == T_SZ - 1) {
#pragma unroll
                for (int r = 0; r < 4; r++)
                    hfin[(g * 16 + quad * 4 + r) * HID + 32 * w + 16 + l15] = hv[r];
            } else {
#pragma unroll
                for (int r = 0; r < 4; r++)
                    h_lds[nbuf][quad * 4 + r][32 * w + 16 + l15] = (bf16_t)hv[r];
            }
        }

        if (t == T_SZ - 1) break;   // uniform exit
        __syncthreads();            // h_{t+1} complete in LDS
    }
}

// ---------------------------------------------------------------------------
// Phase C: logits = h_T @ Wd + bd; softmax. One block per batch row.
// ---------------------------------------------------------------------------
__global__ void head(const float* __restrict__ hfin, const float* __restrict__ Wd,
                     const float* __restrict__ bd, float* __restrict__ out) {
    __shared__ float hrow[HID];
    __shared__ float lg[32];
    __shared__ float ex[32];
    int b = blockIdx.x, tid = threadIdx.x;   // 64 threads
    for (int i = tid; i < HID; i += 64) hrow[i] = hfin[b * HID + i];
    __syncthreads();
    if (tid < NCLS) {
        float acc = bd[tid];
        for (int k = 0; k < HID; k++) acc = fmaf(hrow[k], Wd[k * NCLS + tid], acc);
        lg[tid] = acc;
    }
    __syncthreads();
    if (tid < NCLS) {
        float m = -1e30f;
        for (int jj = 0; jj < NCLS; jj++) m = fmaxf(m, lg[jj]);
        ex[tid] = __expf(lg[tid] - m);
    }
    __syncthreads();
    if (tid < NCLS) {
        float sden = 0.0f;
        for (int jj = 0; jj < NCLS; jj++) sden += ex[jj];
        out[b * NCLS + tid] = ex[tid] / sden;
    }
}

// ---------------------------------------------------------------------------
extern "C" void kernel_launch(void* const* d_in, const int* in_sizes, int n_in,
                              void* d_out, int out_size, void* d_ws, size_t ws_size,
                              hipStream_t stream) {
    const int*   x    = (const int*)d_in[0];
    const float* emb  = (const float*)d_in[1];
    const float* W    = (const float*)d_in[2];
    const float* U    = (const float*)d_in[3];
    const float* bias = (const float*)d_in[4];
    const float* Wd   = (const float*)d_in[5];
    const float* bd   = (const float*)d_in[6];
    float* out = (float*)d_out;

    char* ws = (char*)d_ws;
    bf16_t* Up  = (bf16_t*)(ws + WS_UPACK);
    bf16_t* Wp  = (bf16_t*)(ws + WS_WPACK);
    float*  hf  = (float*)(ws + WS_HFIN);
    bf16x4* xz2 = (bf16x4*)(ws + WS_XZ);

    pack_weights<<<dim3(1024), dim3(256), 0, stream>>>(W, U, Wp, Up);
    xz_gemm<<<dim3(4096), dim3(256), 0, stream>>>(x, emb, Wp, bias, xz2);
    lstm_solo<<<dim3(4), dim3(512), 0, stream>>>(xz2, Up, hf);
    head<<<dim3(64), dim3(64), 0, stream>>>(hf, Wd, bd, out);
}